// Round 5
// baseline (561.475 us; speedup 1.0000x reference)
//
#include <hip/hip_runtime.h>
#include <stdint.h>

// TokenChoiceTopKRouter: x[16384,4096] f32, W[64,4096] f32
//   logits = x@W^T ; sigmoid ; top-8 (lower index wins ties) ; histc
// d_out read back as ONE float32 stream: [scores | float-encoded indices | counts]
//
// Round 5: HBM-bound pass1.
//   - BM=64 (grid 256), 4 waves, each wave = 32tok x 32exp (T2E2), 16x16x32 bf16 MFMA
//   - global_load_lds(16B) double-buffered staging: x as raw fp32, Wh/Wl bf16
//   - XOR source-swizzle (16B granularity) since global_load_lds forbids padding
//   - x split to bf16 h/l in-register (trunc-hi + v_perm pack; hi-err compensated by lo)
//   - logit = xl*wh + xh*wl + xh*wh  (missing xl*wl ~ 1e-5 sigma << GAP_T)
//   - near-tie tokens (adjacent top-9 gap < GAP_T) re-resolved exactly in fp64

#define M_TOK 16384
#define NEXP  64
#define KDIM  4096
#define BM    64
#define BKW   64
#define NWIN  (KDIM / BKW)
#define SCW   68
#define GAP_T 2e-4f

typedef __attribute__((ext_vector_type(8))) short short8;
typedef __attribute__((ext_vector_type(4))) float floatx4;

#define GLD16(g, l) \
    __builtin_amdgcn_global_load_lds((__attribute__((address_space(1))) void*)(g), \
                                     (__attribute__((address_space(3))) void*)(l), 16, 0, 0)
#define MFMA_BF16 __builtin_amdgcn_mfma_f32_16x16x32_bf16

__device__ __forceinline__ uint16_t f2bf(float f) {
    uint32_t u = __float_as_uint(f);
    return (uint16_t)((u + 0x7fffu + ((u >> 16) & 1u)) >> 16);   // RNE
}
__device__ __forceinline__ float bf2f(uint16_t h) {
    return __uint_as_float(((uint32_t)h) << 16);
}
__device__ __forceinline__ uint32_t order32(float f) {
    uint32_t b = __float_as_uint(f);
    return b ^ (((int32_t)b >> 31) | 0x80000000u);
}
__device__ __forceinline__ float unorder32(uint32_t u) {
    uint32_t b = (u & 0x80000000u) ? (u ^ 0x80000000u) : ~u;
    return __uint_as_float(b);
}
__device__ __forceinline__ uint64_t order64(double d) {
    uint64_t b = (uint64_t)__double_as_longlong(d);
    return b ^ (((int64_t)b >> 63) | 0x8000000000000000ull);
}
__device__ __forceinline__ double unorder64(uint64_t u) {
    uint64_t b = (u & 0x8000000000000000ull) ? (u ^ 0x8000000000000000ull) : ~u;
    return __longlong_as_double((int64_t)b);
}
__device__ __forceinline__ void cvt4(const float4 v, ushort4* h, ushort4* l) {
    uint16_t h0 = f2bf(v.x), h1 = f2bf(v.y), h2 = f2bf(v.z), h3 = f2bf(v.w);
    *h = make_ushort4(h0, h1, h2, h3);
    *l = make_ushort4(f2bf(v.x - bf2f(h0)), f2bf(v.y - bf2f(h1)),
                      f2bf(v.z - bf2f(h2)), f2bf(v.w - bf2f(h3)));
}
// 8 fp32 -> bf16 hi (trunc) + bf16 lo (trunc of residual), packed via v_perm.
// hi-trunc error is exactly carried into lo; net residual ~2^-16 rel.
__device__ __forceinline__ void cvt8(float4 q0, float4 q1, short8* h, short8* l) {
    union { uint32_t u[4]; short8 v; } H, L;
    float f[8] = {q0.x, q0.y, q0.z, q0.w, q1.x, q1.y, q1.z, q1.w};
    #pragma unroll
    for (int i = 0; i < 4; ++i) {
        uint32_t u0 = __float_as_uint(f[2 * i]);
        uint32_t u1 = __float_as_uint(f[2 * i + 1]);
        H.u[i] = __builtin_amdgcn_perm(u1, u0, 0x07060302u);
        float l0 = f[2 * i]     - __uint_as_float(u0 & 0xffff0000u);
        float l1 = f[2 * i + 1] - __uint_as_float(u1 & 0xffff0000u);
        L.u[i] = __builtin_amdgcn_perm(__float_as_uint(l1), __float_as_uint(l0), 0x07060302u);
    }
    *h = H.v; *l = L.v;
}

// W fp32 -> (Wh, Wl) bf16 (RNE) + zero-init counts/flag_cnt (replaces memsets)
__global__ __launch_bounds__(256) void w_split(
    const float* __restrict__ W, uint16_t* __restrict__ Wh, uint16_t* __restrict__ Wl,
    float* __restrict__ counts, unsigned int* __restrict__ flag_cnt)
{
    if (blockIdx.x == 0) {
        if (threadIdx.x < NEXP) counts[threadIdx.x] = 0.0f;
        if (threadIdx.x == 64) *flag_cnt = 0u;
    }
    const int idx = (blockIdx.x * 256 + threadIdx.x) * 4;
    const float4 w = *(const float4*)(W + idx);
    ushort4 h, l;
    cvt4(w, &h, &l);
    *(ushort4*)(Wh + idx) = h;
    *(ushort4*)(Wl + idx) = l;
}

__global__ __launch_bounds__(256) void router_pass1(
    const float* __restrict__ x,
    const uint16_t* __restrict__ Whg, const uint16_t* __restrict__ Wlg,
    float* __restrict__ top_scores, float* __restrict__ top_idx,
    float* __restrict__ counts, unsigned int* __restrict__ flag_cnt,
    int* __restrict__ flag_list, int cap)
{
    // 2 buffers x 32KB: [x fp32 64x256B | Wh 64x128B | Wl 64x128B], no padding
    // (global_load_lds needs linear lane order) -> XOR swizzle on global source.
    __shared__ __align__(16) char smem[65536];

    const int tid  = threadIdx.x;
    const int wave = tid >> 6, lane = tid & 63;
    const int wm = wave >> 1, wn = wave & 1;        // token half / expert half
    const int quad = lane >> 4, r = lane & 15;
    const int m0 = blockIdx.x * BM;

    auto issue = [&](int w) {
        const int k0 = w * BKW;
        char* b = smem + ((w & 1) << 15);
        #pragma unroll
        for (int j = 0; j < 4; ++j) {               // x: 4 rows per instr
            const int row = (wave << 4) + (j << 2) + (lane >> 4);
            const int g = (lane & 15) ^ (row & 7);  // 16B-chunk swizzle
            const float* gp = x + (size_t)(m0 + row) * KDIM + k0 + g * 4;
            char* lp = b + (((wave << 4) + (j << 2)) << 8);
            GLD16(gp, lp);
        }
        #pragma unroll
        for (int j = 0; j < 2; ++j) {               // Wh/Wl: 8 rows per instr
            const int row = (wave << 4) + (j << 3) + (lane >> 3);
            const int c = (lane & 7) ^ (row & 7);
            const uint16_t* gph = Whg + (size_t)row * KDIM + k0 + c * 8;
            const uint16_t* gpl = Wlg + (size_t)row * KDIM + k0 + c * 8;
            char* lb = b + (((wave << 4) + (j << 3)) << 7);
            GLD16(gph, lb + 16384);
            GLD16(gpl, lb + 24576);
        }
    };

    floatx4 acc[2][2] = {{{0.f,0.f,0.f,0.f},{0.f,0.f,0.f,0.f}},
                         {{0.f,0.f,0.f,0.f},{0.f,0.f,0.f,0.f}}};

    issue(0);
    for (int w = 0; w < NWIN; ++w) {
        __syncthreads();                 // drains window-w loads (issued 1 window ago)
        if (w + 1 < NWIN) issue(w + 1);  // safe: all waves past compute(w-1)

        const char* b   = smem + ((w & 1) << 15);
        const char* whb = b + 16384;
        const char* wlb = b + 24576;
        #pragma unroll
        for (int s = 0; s < 2; ++s) {
            short8 ah[2], al[2], bh[2], bl[2];
            #pragma unroll
            for (int tm = 0; tm < 2; ++tm) {
                const int row = wm * 32 + tm * 16 + r;
                const int h0 = s * 8 + quad * 2;
                const float* xrow = (const float*)(b + (row << 8));
                float4 q0 = *(const float4*)(xrow + (((h0)     ^ (row & 7)) << 2));
                float4 q1 = *(const float4*)(xrow + (((h0 + 1) ^ (row & 7)) << 2));
                cvt8(q0, q1, &ah[tm], &al[tm]);
            }
            #pragma unroll
            for (int tn = 0; tn < 2; ++tn) {
                const int e = wn * 32 + tn * 16 + r;
                const int c = (s * 4 + quad) ^ (e & 7);
                bh[tn] = *(const short8*)(whb + (e << 7) + (c << 4));
                bl[tn] = *(const short8*)(wlb + (e << 7) + (c << 4));
            }
            #pragma unroll
            for (int tm = 0; tm < 2; ++tm)
                #pragma unroll
                for (int tn = 0; tn < 2; ++tn) {
                    acc[tm][tn] = MFMA_BF16(al[tm], bh[tn], acc[tm][tn], 0, 0, 0);
                    acc[tm][tn] = MFMA_BF16(ah[tm], bl[tn], acc[tm][tn], 0, 0, 0);
                    acc[tm][tn] = MFMA_BF16(ah[tm], bh[tn], acc[tm][tn], 0, 0, 0);
                }
        }
    }
    __syncthreads();   // last window's reads done; smem reusable

    float* sc   = (float*)smem;            // 64 x 68 f32 = 17408 B (buf0)
    float* hist = (float*)(smem + 32768);  // buf1
    // C/D layout: col = lane&15 (expert), row = quad*4 + reg (token)  [verified r3/r4]
    #pragma unroll
    for (int tm = 0; tm < 2; ++tm)
        #pragma unroll
        for (int tn = 0; tn < 2; ++tn)
            #pragma unroll
            for (int i = 0; i < 4; ++i)
                sc[(wm * 32 + tm * 16 + quad * 4 + i) * SCW + wn * 32 + tn * 16 + r] =
                    acc[tm][tn][i];
    if (tid < NEXP) hist[tid] = 0.0f;
    __syncthreads();

    // top-9 by logit, flag near-ties, write outputs (validated r3/r4)
    for (int t = wave * 16; t < wave * 16 + 16; ++t) {
        const float logit = sc[t * SCW + lane];
        uint32_t u = order32(logit);
        float win_logit = 0.0f;
        int win_idx = 0;
        #pragma unroll
        for (int rr = 0; rr < 9; ++rr) {
            unsigned long long key = ((unsigned long long)u << 32) | (uint32_t)(63 - lane);
            #pragma unroll
            for (int off = 32; off > 0; off >>= 1) {
                const unsigned long long o = __shfl_xor(key, off, 64);
                key = (key > o) ? key : o;
            }
            const int widx = 63 - (int)(key & 0xffffffffu);
            if (lane == rr) { win_logit = unorder32((uint32_t)(key >> 32)); win_idx = widx; }
            if (lane == widx) u = 0;
        }
        const float prev = __shfl_up(win_logit, 1, 64);
        const bool close = (lane >= 1 && lane <= 8) && (prev - win_logit < GAP_T);
        const unsigned long long bal = __ballot(close);
        const int token = m0 + t;
        if (lane == 0 && bal != 0ull) {
            const unsigned int slot = atomicAdd(flag_cnt, 1u);
            if ((int)slot < cap) flag_list[slot] = token;
        }
        if (lane < 8) {
            top_scores[(size_t)token * 8 + lane] = 1.0f / (1.0f + expf(-win_logit));
            top_idx[(size_t)token * 8 + lane] = (float)win_idx;   // float-encoded index
            atomicAdd(&hist[win_idx], 1.0f);
        }
    }
    __syncthreads();
    if (tid < NEXP) atomicAdd(&counts[tid], hist[tid]);
}

// fp64 exact re-resolution, coalesced (validated r4)
__global__ __launch_bounds__(256, 2) void router_fixup(
    const float* __restrict__ x, const float* __restrict__ W,
    float* __restrict__ top_scores, float* __restrict__ top_idx,
    float* __restrict__ counts, const unsigned int* __restrict__ flag_cnt,
    const int* __restrict__ flag_list, int cap)
{
    __shared__ double logits[NEXP];
    const int n = (int)min(*flag_cnt, (unsigned int)cap);
    const int tid = threadIdx.x;
    const int wave = tid >> 6, lane = tid & 63;

    for (int i = blockIdx.x; i < n; i += gridDim.x) {
        const int tok = flag_list[i];
        const float4* xp = (const float4*)(x + (size_t)tok * KDIM);
        for (int j = 0; j < 16; ++j) {
            const int e = wave * 16 + j;
            const float4* wp = (const float4*)(W + (size_t)e * KDIM);
            double s = 0.0;
            for (int c = lane; c < KDIM / 4; c += 64) {
                const float4 a = xp[c], b = wp[c];
                s += (double)a.x * (double)b.x + (double)a.y * (double)b.y
                   + (double)a.z * (double)b.z + (double)a.w * (double)b.w;
            }
            #pragma unroll
            for (int off = 32; off > 0; off >>= 1) s += __shfl_down(s, off, 64);
            if (lane == 0) logits[e] = s;
        }
        __syncthreads();
        if (tid < 64) {
            const float oldv = (tid < 8) ? top_idx[(size_t)tok * 8 + tid] : 0.0f;
            uint64_t u = (order64(logits[tid]) & ~63ull) | (uint64_t)(63 - tid);
            #pragma unroll
            for (int rr = 0; rr < 8; ++rr) {
                uint64_t key = u;
                #pragma unroll
                for (int off = 32; off > 0; off >>= 1) {
                    const uint64_t o = __shfl_xor((unsigned long long)key, off, 64);
                    key = (key > o) ? key : o;
                }
                const int widx = 63 - (int)(key & 63ull);
                if (tid == rr) {
                    const double z = unorder64(key);
                    atomicAdd(&counts[(int)oldv], -1.0f);
                    atomicAdd(&counts[widx], 1.0f);
                    top_scores[(size_t)tok * 8 + tid] = (float)(1.0 / (1.0 + exp(-z)));
                    top_idx[(size_t)tok * 8 + tid] = (float)widx;
                }
                if (tid == widx) u = 0;
            }
        }
        __syncthreads();
    }
}

extern "C" void kernel_launch(void* const* d_in, const int* in_sizes, int n_in,
                              void* d_out, int out_size, void* d_ws, size_t ws_size,
                              hipStream_t stream) {
    (void)in_sizes; (void)n_in; (void)out_size; (void)ws_size;
    const float* x = (const float*)d_in[0];
    const float* W = (const float*)d_in[1];

    float* top_scores = (float*)d_out;
    float* top_idx    = (float*)d_out + (size_t)M_TOK * 8;
    float* counts     = (float*)d_out + (size_t)2 * M_TOK * 8;

    // ws: [0,64B) flag_cnt | [64B,128KB) flag_list | [128KB..) Wh, Wl
    unsigned int* flag_cnt  = (unsigned int*)d_ws;
    int*          flag_list = (int*)d_ws + 16;
    uint16_t*     Whg = (uint16_t*)((char*)d_ws + (128 << 10));
    uint16_t*     Wlg = Whg + (size_t)NEXP * KDIM;
    const int cap = 16384;

    w_split<<<256, 256, 0, stream>>>(W, Whg, Wlg, counts, flag_cnt);
    router_pass1<<<M_TOK / BM, 256, 0, stream>>>(x, Whg, Wlg, top_scores, top_idx,
                                                 counts, flag_cnt, flag_list, cap);
    router_fixup<<<256, 256, 0, stream>>>(x, W, top_scores, top_idx,
                                          counts, flag_cnt, flag_list, cap);
}